// Round 11
// baseline (21.133 us; speedup 1.0000x reference)
//
#include <hip/hip_runtime.h>
#include <cstdint>
#include <cstddef>

#define BATCH 4
#define NTOK  4096
#define CCH   256
#define IMH   512
#define IMW   512

#define RPB 16                                  // rows per block: 4 waves x 4 rows
#define NBLOCKS (BATCH * NTOK / RPB)            // 1024

typedef float v4f __attribute__((ext_vector_type(4)));

// ---------------------------------------------------------------------------
// Round-11: MLP lever applied harder.
//  - dis reformulated on aligned float4: patch col base = px*16B, so each
//    (row, ch, patch-row) unit loads C/U/D as one float4 + 2 edge scalars
//    (60 loads/row vs 240 scalar); horizontal diffs from registers.
//  - dis loads issued BEFORE the scan (depend only on po keys) -> their
//    latency hides under the scan burst + compare VALU.
//  - gather: 4 independent rows per wave, unrolled (static reg indices).
//  - scan: 8-deep int4 burst, 16 keys in registers, redundancy halved.
// ---------------------------------------------------------------------------
__global__ __launch_bounds__(256) void fused_k(const float4* __restrict__ feat,
                                               const float* __restrict__ im,
                                               const int2* __restrict__ po,
                                               const int4* __restrict__ ps4,
                                               float4* __restrict__ out_feat,
                                               float* __restrict__ out_dis) {
    __shared__ int s_key[RPB];
    __shared__ int s_idx[RPB];

    const int tid = threadIdx.x;
    const int r0  = blockIdx.x * RPB;           // 256 blocks per batch
    const int b   = blockIdx.x >> 8;

    if (tid < RPB) {
        int2 p = po[r0 + tid];
        s_key[tid] = (p.x << 16) | p.y;
        s_idx[tid] = 0x7FFFFFFF;
    }
    __syncthreads();

    const int lane = tid & 63;
    const int w    = tid >> 6;

    // ---- dis: issue loads EARLY (depend only on keys, not on scan) ----
    // lane&15 = unit (<12 active: ch=unit>>2, patch-row=unit&3); lane>>4 = q
    const int q    = lane >> 4;                 // local row 0..3
    const int unit = lane & 15;
    const int drow = r0 + w * 4 + q;
    const int dkey = s_key[w * 4 + q];
    const bool act = unit < 12;

    const int px = dkey >> 16, py = dkey & 0xFFFF;
    const int ch = unit >> 2,  pr = unit & 3;
    const int rimg = py * 4 + pr;               // image row; D row <= 496 ok
    const int col0 = px * 4;                    // 16B-aligned float4 col base
    const float* dbase = im + (((size_t)(b * 3 + ch)) * IMH + rimg) * IMW + col0;

    v4f vC = {0,0,0,0}, vU = {0,0,0,0}, vD = {0,0,0,0};
    float vL = 0.f, vR = 0.f;
    if (act) {
        vC = *(const v4f*)dbase;
        vU = *(const v4f*)(rimg > 0 ? dbase - IMW : dbase);   // clamped, masked later
        vD = *(const v4f*)(dbase + IMW);                      // always in-bounds
        vL = (col0 > 0) ? dbase[-1] : 0.f;
        vR = dbase[4];                                        // col<=496 ok
    }

    // ---- scan: 8-deep independent int4 burst, then compare burst ----
    int kreg[RPB];
#pragma unroll
    for (int k = 0; k < RPB; ++k) kreg[k] = s_key[k];

    const int4* psb = ps4 + (size_t)b * (NTOK / 2);
    int4 t[8];
#pragma unroll
    for (int it = 0; it < 8; ++it) t[it] = psb[it * 256 + tid];

#pragma unroll
    for (int it = 0; it < 8; ++it) {
        const int e0 = (t[it].x << 16) | t[it].y;
        const int e1 = (t[it].z << 16) | t[it].w;
        const int j0 = 2 * (it * 256 + tid);
#pragma unroll
        for (int k = 0; k < RPB; ++k) {
            if (e0 == kreg[k]) atomicMin(&s_idx[k], j0);
            if (e1 == kreg[k]) atomicMin(&s_idx[k], j0 + 1);
        }
    }
    __syncthreads();

    // ---- gather: 4 independent rows per wave (static unroll, no scratch) ----
#pragma unroll
    for (int qq = 0; qq < 4; ++qq) {
        const int row = r0 + w * 4 + qq;
        const int idx = s_idx[w * 4 + qq];
        const float4 f = feat[((size_t)(b * NTOK + idx)) * 64 + lane];
        v4f n = { f.x, f.y, f.z, f.w };
        __builtin_nontemporal_store(n, (v4f*)&out_feat[(size_t)row * 64 + lane]);
    }

    // ---- dis: compute from the early loads ----
    float s = 0.f;
    if (act) {
        const float su = fabsf(vC.x - vU.x) + fabsf(vC.y - vU.y)
                       + fabsf(vC.z - vU.z) + fabsf(vC.w - vU.w);
        if (rimg > 0) s += su;
        s += fabsf(vD.x - vC.x) + fabsf(vD.y - vC.y)
           + fabsf(vD.z - vC.z) + fabsf(vD.w - vC.w);
        const float d01 = fabsf(vC.y - vC.x);
        const float d12 = fabsf(vC.z - vC.y);
        const float d23 = fabsf(vC.w - vC.z);
        s += 2.f * (d01 + d12 + d23);
        if (col0 > 0) s += fabsf(vC.x - vL);
        s += fabsf(vR - vC.w);
    }
    // reduce the 16-lane group (12 active units) to one row sum
    s += __shfl_xor(s, 1, 16);
    s += __shfl_xor(s, 2, 16);
    s += __shfl_xor(s, 4, 16);
    s += __shfl_xor(s, 8, 16);
    if (unit == 0) __builtin_nontemporal_store(s, &out_dis[drow]);
}

extern "C" void kernel_launch(void* const* d_in, const int* in_sizes, int n_in,
                              void* d_out, int out_size, void* d_ws, size_t ws_size,
                              hipStream_t stream) {
    const float* feat         = (const float*)d_in[0];
    const float* images       = (const float*)d_in[1];
    const int*   pos_org      = (const int*)d_in[2];
    const int*   pos_shuffled = (const int*)d_in[3];

    float* out_feat = (float*)d_out;
    float* out_dis  = out_feat + (size_t)BATCH * NTOK * CCH;

    fused_k<<<NBLOCKS, 256, 0, stream>>>(
        (const float4*)feat, images, (const int2*)pos_org,
        (const int4*)pos_shuffled, (float4*)out_feat, out_dis);
}

// Round 12
// 18.211 us; speedup vs baseline: 1.1605x; 1.1605x over previous
//
#include <hip/hip_runtime.h>
#include <cstdint>
#include <cstddef>

#define BATCH 4
#define NTOK  4096
#define CCH   256
#define IMH   512
#define IMW   512

#define RPB 8                                   // rows per block
#define NBLOCKS (BATCH * NTOK / RPB)            // 2048 blocks = 8 waves/SIMD

typedef float v4f __attribute__((ext_vector_type(4)));

// ---------------------------------------------------------------------------
// Round-12: R10's proven-optimal occupancy (2048 blocks) + R11's float4 dis.
//  - dis: patch col base = px*16B aligned -> per (row, ch, patch-row) unit:
//    C/U/D as float4 + 2 edge scalars (60 loads/row vs 240 scalar). Issued
//    BEFORE the scan (depends only on po keys) so latency hides under the
//    scan burst + compare VALU. Wave w: 16-lane groups 0,1 -> rows 2w, 2w+1.
//  - scan: 8-deep independent int4 burst, 8 keys in registers, compare burst.
//  - gather: 2 independent rows per wave, cached loads (feat L3-resident),
//    nontemporal stores (streaming out).
// ---------------------------------------------------------------------------
__global__ __launch_bounds__(256) void fused_k(const float4* __restrict__ feat,
                                               const float* __restrict__ im,
                                               const int2* __restrict__ po,
                                               const int4* __restrict__ ps4,
                                               float4* __restrict__ out_feat,
                                               float* __restrict__ out_dis) {
    __shared__ int s_key[RPB];
    __shared__ int s_idx[RPB];

    const int tid = threadIdx.x;
    const int r0  = blockIdx.x * RPB;           // 512 blocks per batch
    const int b   = blockIdx.x >> 9;

    if (tid < RPB) {
        int2 p = po[r0 + tid];
        s_key[tid] = (p.x << 16) | p.y;
        s_idx[tid] = 0x7FFFFFFF;
    }
    __syncthreads();

    const int lane = tid & 63;
    const int w    = tid >> 6;

    // ---- dis loads: EARLY (depend only on keys). groups 0,1 own the wave's
    //      two rows; 12 active units per group = (ch 0..2) x (patch-row 0..3).
    const int group = lane >> 4;                // 0..3
    const int unit  = lane & 15;
    const bool dact = (group < 2) && (unit < 12);
    const int dli   = w * 2 + group;            // local row (valid when group<2)
    const int dkey  = s_key[dli & (RPB - 1)];

    const int px = dkey >> 16, py = dkey & 0xFFFF;
    const int ch = unit >> 2,  pr = unit & 3;
    const int rimg = py * 4 + pr;               // <= 495; +IMW row <= 496 ok
    const int col0 = px * 4;                    // 16B-aligned; col0+4 <= 496 ok
    const float* dbase = im + (((size_t)(b * 3 + ch)) * IMH + rimg) * IMW + col0;

    v4f vC = {0,0,0,0}, vU = {0,0,0,0}, vD = {0,0,0,0};
    float vL = 0.f, vR = 0.f;
    if (dact) {
        vC = *(const v4f*)dbase;
        vU = *(const v4f*)(rimg > 0 ? dbase - IMW : dbase);   // clamped; masked below
        vD = *(const v4f*)(dbase + IMW);
        vL = (col0 > 0) ? dbase[-1] : 0.f;
        vR = dbase[4];
    }

    // ---- scan: 8-deep independent int4 burst, then compare burst ----
    int kreg[RPB];
#pragma unroll
    for (int k = 0; k < RPB; ++k) kreg[k] = s_key[k];

    const int4* psb = ps4 + (size_t)b * (NTOK / 2);
    int4 t[8];
#pragma unroll
    for (int it = 0; it < 8; ++it) t[it] = psb[it * 256 + tid];

#pragma unroll
    for (int it = 0; it < 8; ++it) {
        const int e0 = (t[it].x << 16) | t[it].y;
        const int e1 = (t[it].z << 16) | t[it].w;
        const int j0 = 2 * (it * 256 + tid);
#pragma unroll
        for (int k = 0; k < RPB; ++k) {
            if (e0 == kreg[k]) atomicMin(&s_idx[k], j0);
            if (e1 == kreg[k]) atomicMin(&s_idx[k], j0 + 1);
        }
    }
    __syncthreads();

    // ---- gather: 2 independent rows per wave ----
    const int row0 = r0 + w * 2,     row1 = row0 + 1;
    const int idx0 = s_idx[w * 2],   idx1 = s_idx[w * 2 + 1];

    const float4 f0 = feat[((size_t)(b * NTOK + idx0)) * 64 + lane];
    const float4 f1 = feat[((size_t)(b * NTOK + idx1)) * 64 + lane];
    v4f n0 = { f0.x, f0.y, f0.z, f0.w };
    v4f n1 = { f1.x, f1.y, f1.z, f1.w };
    __builtin_nontemporal_store(n0, (v4f*)&out_feat[(size_t)row0 * 64 + lane]);
    __builtin_nontemporal_store(n1, (v4f*)&out_feat[(size_t)row1 * 64 + lane]);

    // ---- dis compute from the early loads ----
    float s = 0.f;
    if (dact) {
        if (rimg > 0)
            s += fabsf(vC.x - vU.x) + fabsf(vC.y - vU.y)
               + fabsf(vC.z - vU.z) + fabsf(vC.w - vU.w);
        s += fabsf(vD.x - vC.x) + fabsf(vD.y - vC.y)
           + fabsf(vD.z - vC.z) + fabsf(vD.w - vC.w);
        const float d01 = fabsf(vC.y - vC.x);
        const float d12 = fabsf(vC.z - vC.y);
        const float d23 = fabsf(vC.w - vC.z);
        s += 2.f * (d01 + d12 + d23);
        if (col0 > 0) s += fabsf(vC.x - vL);
        s += fabsf(vR - vC.w);
    }
    // reduce within the 16-lane group (units 12..15 contribute 0)
    s += __shfl_xor(s, 1, 16);
    s += __shfl_xor(s, 2, 16);
    s += __shfl_xor(s, 4, 16);
    s += __shfl_xor(s, 8, 16);
    if (group < 2 && unit == 0)
        __builtin_nontemporal_store(s, &out_dis[r0 + w * 2 + group]);
}

extern "C" void kernel_launch(void* const* d_in, const int* in_sizes, int n_in,
                              void* d_out, int out_size, void* d_ws, size_t ws_size,
                              hipStream_t stream) {
    const float* feat         = (const float*)d_in[0];
    const float* images       = (const float*)d_in[1];
    const int*   pos_org      = (const int*)d_in[2];
    const int*   pos_shuffled = (const int*)d_in[3];

    float* out_feat = (float*)d_out;
    float* out_dis  = out_feat + (size_t)BATCH * NTOK * CCH;

    fused_k<<<NBLOCKS, 256, 0, stream>>>(
        (const float4*)feat, images, (const int2*)pos_org,
        (const int4*)pos_shuffled, (float4*)out_feat, out_dis);
}